// Round 6
// baseline (120.237 us; speedup 1.0000x reference)
//
#include <hip/hip_runtime.h>

#define NT 256

constexpr int L0 = 8192;
constexpr int N1 = 4099;   // (8192+7)>>1
constexpr int N2 = 2053;   // (4099+7)>>1
constexpr int N3 = 1030;   // (2053+7)>>1
constexpr int N4 = 518;    // (1030+7)>>1
constexpr int ROW_OUT = N4 + N4 + N3 + N2 + N1;  // 8218
constexpr int OFF_A4 = 0;
constexpr int OFF_D4 = 518;
constexpr int OFF_D3 = 1036;
constexpr int OFF_D2 = 2066;
constexpr int OFF_D1 = 4119;

// Per-wave LDS region (floats), zero cross-wave sharing:
//   s1 [0,576)     cA1 ext strip (pos = c - B1 = 9l+m)
//   R  [576,1152)  T1 cD1-transpose strip in L1; after its reads:
//                  s2 = R[0,320) (cA2, pos = 5l+m), T3 = R[320,512) (cD3 strip)
//   C  [1152,1472) T2 cD2-transpose strip in L2; after its reads:
//                  s3 = C[0,192) (cA3, pos = 3l+m)
// Strip writes have odd stride (9/5/3) -> bank-conflict-free; strip reads are
// 64 consecutive floats -> 2-way (free). Overshoot reads land in the wave's
// own region and only feed guarded (never-stored) outputs.
constexpr int SW = 1472;   // floats per wave; 4 waves = 23552 B -> 6 blocks/CU

// lo[i] = sum_j GLO[j] * xsym(2i-6+j)   (GLO = pywt db4 rec_lo = dec_lo reversed)
constexpr float GLO[8] = {
    0.23037781330885523f,  0.7148465705525415f,   0.6308807679295904f,
   -0.02798376941698385f, -0.18703481171888114f,  0.030841381835986965f,
    0.032883011666982945f, -0.010597401784997278f };
// hi[i] = sum_j GHI[j] * xsym(2i-6+j)
constexpr float GHI[8] = {
   -0.010597401784997278f, -0.032883011666982945f, 0.030841381835986965f,
    0.18703481171888114f,  -0.02798376941698385f,  -0.6308807679295904f,
    0.7148465705525415f,   -0.23037781330885523f };

// Identical ascending-j fmaf chain as all verified rounds -> bit-exact.
__device__ __forceinline__ void conv1(const float* __restrict__ w,
                                      float& lo, float& hi)
{
    float l = 0.f, h = 0.f;
#pragma unroll
    for (int j = 0; j < 8; ++j) {
        float v = w[j];
        l = fmaf(GLO[j], v, l);
        h = fmaf(GHI[j], v, h);
    }
    lo = l; hi = h;
}

// Barrier-free wave cascade (round-4 structure, verified bit-exact) with
// wave-private LDS transpose strips (round-5 technique, verified bit-exact)
// so every bulk global store is 64-lane-consecutive. NO __syncthreads and no
// vmcnt(0) store drains anywhere: the store stream flows continuously.
__global__ __launch_bounds__(NT, 8) void wavedec4_db4(const float* __restrict__ x,
                                                      float* __restrict__ out)
{
    __shared__ float lds[4 * SW];   // 23552 B
    const int tid = threadIdx.x;
    const int widx = tid >> 6;
    const int l = tid & 63;
    const int gw = blockIdx.x * 4 + widx;   // global wave id
    const int row = gw >> 3;
    const int w = gw & 7;                    // wave's slice of the row

    const float* __restrict__ xr = x + (size_t)row * L0;
    float* __restrict__ outr = out + (size_t)row * ROW_OUT;
    float* __restrict__ s1 = lds + widx * SW;
    float* __restrict__ R  = s1 + 576;
    float* __restrict__ C  = s1 + 1152;

    const int B1 = 512 * w - 48;             // cA1 ext base
    const int B2 = 256 * w - 18;             // cA2 ext base
    const int B3 = 128 * w - 6;              // cA3 ext base
    const bool interior = (w != 0) && (w != 7);

    // ---- L1: 24 x-floats per lane, 9 cA1/cD1 outputs per lane ----
    float xw[24];
    const int bl = 2 * B1 - 6 + 18 * l;      // x window base (even)
    if (bl >= 0 && bl + 24 <= L0) {
        const float2* p = (const float2*)(xr + bl);
#pragma unroll
        for (int k = 0; k < 12; ++k) { float2 v = p[k]; xw[2 * k] = v.x; xw[2 * k + 1] = v.y; }
    } else {
#pragma unroll
        for (int k = 0; k < 24; ++k) {
            int q = bl + k;
            q = (q < 0) ? (-1 - q) : q;
            q = (q >= L0) ? (2 * L0 - 1 - q) : q;
            xw[k] = xr[q];
        }
    }
#pragma unroll
    for (int m = 0; m < 9; ++m) {
        float lo, hi;
        conv1(xw + 2 * m, lo, hi);
        s1[9 * l + m] = lo;                  // pos = c - B1
        R[9 * l + m] = hi;                   // T1 strip, stride-9
    }
    {   // coalesced cD1: c = 512w + 64k + l  <->  T1 pos = c - B1 = 48 + 64k + l
        float* d1 = outr + OFF_D1 + 512 * w + l;
#pragma unroll
        for (int k = 0; k < 8; ++k) d1[64 * k] = R[48 + 64 * k + l];
        if (w == 7 && l < 3) d1[512] = R[560 + l];   // c = 4096..4098
    }
    __builtin_amdgcn_wave_barrier();         // pin T1 reads before s2 overlay writes

    // ---- L2: window = cA1_sym[2c2-6 ..], c2 = B2 + 5l + m, m<5 ----
    float wb[16];
    if (interior) {
        const float2* p = (const float2*)(s1 + 10 * l + 6);   // pos = 6+10l, even
#pragma unroll
        for (int k = 0; k < 8; ++k) { float2 v = p[k]; wb[2 * k] = v.x; wb[2 * k + 1] = v.y; }
    } else {
        const int g0 = 2 * B2 - 6 + 10 * l;  // level-1 index of window start
#pragma unroll
        for (int k = 0; k < 16; ++k) {
            int g = g0 + k;
            g = (g < 0) ? (-1 - g) : g;
            g = (g >= N1) ? (2 * N1 - 1 - g) : g;
            wb[k] = s1[g - B1];
        }
    }
    float* __restrict__ s2 = R;              // overlays dead T1
    float* __restrict__ T2 = C;
#pragma unroll
    for (int m = 0; m < 5; ++m) {
        float lo, hi;
        conv1(wb + 2 * m, lo, hi);
        s2[5 * l + m] = lo;                  // pos = c - B2
        T2[5 * l + m] = hi;                  // T2 strip, stride-5
    }
    {   // coalesced cD2: c = 256w + 64k + l  <->  pos = 18 + 64k + l
        float* d2 = outr + OFF_D2 + 256 * w + l;
#pragma unroll
        for (int k = 0; k < 4; ++k) d2[64 * k] = T2[18 + 64 * k + l];
        if (w == 7 && l < 5) d2[256] = T2[274 + l];  // c = 2048..2052
    }
    __builtin_amdgcn_wave_barrier();         // pin T2 reads before s3 overlay writes

    // ---- L3: window = cA2_sym[2c3-6 ..], c3 = B3 + 3l + m, m<3 ----
    float wc[12];
    if (interior) {
        const float2* p = (const float2*)(s2 + 6 * l);        // pos = 6l, even
#pragma unroll
        for (int k = 0; k < 6; ++k) { float2 v = p[k]; wc[2 * k] = v.x; wc[2 * k + 1] = v.y; }
    } else {
        const int g0 = 2 * B3 - 6 + 6 * l;
#pragma unroll
        for (int k = 0; k < 12; ++k) {
            int g = g0 + k;
            g = (g < 0) ? (-1 - g) : g;
            g = (g >= N2) ? (2 * N2 - 1 - g) : g;
            wc[k] = s2[g - B2];
        }
    }
    float* __restrict__ s3 = C;              // overlays dead T2
    float* __restrict__ T3 = R + 320;        // spare behind s2
#pragma unroll
    for (int m = 0; m < 3; ++m) {
        float lo, hi;
        conv1(wc + 2 * m, lo, hi);
        s3[3 * l + m] = lo;                  // pos = c - B3
        T3[3 * l + m] = hi;                  // T3 strip, stride-3
    }
    {   // coalesced cD3: c = 128w + 64k + l  <->  pos = 6 + 64k + l
        float* d3 = outr + OFF_D3 + 128 * w + l;
#pragma unroll
        for (int k = 0; k < 2; ++k) d3[64 * k] = T3[6 + 64 * k + l];
        if (w == 7 && l < 6) d3[128] = T3[134 + l];  // c = 1024..1029
    }

    // ---- L4: one output per lane, c4 = 64w + l (already lane-consecutive) ----
    float wd[8];
    if (interior) {
        const float2* p = (const float2*)(s3 + 2 * l);        // pos = 2l, even
#pragma unroll
        for (int k = 0; k < 4; ++k) { float2 v = p[k]; wd[2 * k] = v.x; wd[2 * k + 1] = v.y; }
    } else {
        const int g0 = 128 * w - 6 + 2 * l;
#pragma unroll
        for (int k = 0; k < 8; ++k) {
            int g = g0 + k;
            g = (g < 0) ? (-1 - g) : g;
            g = (g >= N3) ? (2 * N3 - 1 - g) : g;
            wd[k] = s3[g - B3];
        }
    }
    {
        float lo, hi;
        conv1(wd, lo, hi);
        const int c = 64 * w + l;
        outr[OFF_A4 + c] = lo;
        outr[OFF_D4 + c] = hi;
    }
    // L4 tail (outputs 512..517), wave 7 lanes 0..5, with right reflection
    if (w == 7 && l < 6) {
        float we[8];
#pragma unroll
        for (int k = 0; k < 8; ++k) {
            int g = 1018 + 2 * l + k;        // 2*(512+l)-6+k
            g = (g >= N3) ? (2 * N3 - 1 - g) : g;
            we[k] = s3[g - B3];
        }
        float lo, hi;
        conv1(we, lo, hi);
        const int c = 512 + l;
        outr[OFF_A4 + c] = lo;
        outr[OFF_D4 + c] = hi;
    }
}

extern "C" void kernel_launch(void* const* d_in, const int* in_sizes, int n_in,
                              void* d_out, int out_size, void* d_ws, size_t ws_size,
                              hipStream_t stream) {
    const float* x = (const float*)d_in[0];
    float* out = (float*)d_out;
    const int rows = in_sizes[0] / L0;   // 64*32 = 2048
    // 8 waves per row, 4 waves per 256-thread block -> 2 blocks per row
    wavedec4_db4<<<dim3(rows * 2), dim3(NT), 0, stream>>>(x, out);
}

// Round 7
// 110.677 us; speedup vs baseline: 1.0864x; 1.0864x over previous
//
#include <hip/hip_runtime.h>

#define NT 512

constexpr int L0 = 8192;
constexpr int N1 = 4099;   // (8192+7)>>1
constexpr int N2 = 2053;   // (4099+7)>>1
constexpr int N3 = 1030;   // (2053+7)>>1
constexpr int N4 = 518;    // (1030+7)>>1
constexpr int ROW_OUT = N4 + N4 + N3 + N2 + N1;  // 8218
constexpr int OFF_A4 = 0;
constexpr int OFF_D4 = 518;
constexpr int OFF_D3 = 1036;
constexpr int OFF_D2 = 2066;
constexpr int OFF_D1 = 4119;

// Halo SoA stride (slots per coefficient lane).
constexpr int HS = 520;

// 4-byte-aligned vector types: out-row offsets (4119+8t etc.) are only
// dword-aligned; gfx950 global multi-dword ops need 4B alignment only.
typedef float f4u __attribute__((ext_vector_type(4), aligned(4)));
typedef float f2u __attribute__((ext_vector_type(2), aligned(4)));

// lo[i] = sum_j GLO[j] * xsym(2i-6+j)   (GLO = pywt db4 rec_lo = dec_lo reversed)
constexpr float GLO[8] = {
    0.23037781330885523f,  0.7148465705525415f,   0.6308807679295904f,
   -0.02798376941698385f, -0.18703481171888114f,  0.030841381835986965f,
    0.032883011666982945f, -0.010597401784997278f };
// hi[i] = sum_j GHI[j] * xsym(2i-6+j)
constexpr float GHI[8] = {
   -0.010597401784997278f, -0.032883011666982945f, 0.030841381835986965f,
    0.18703481171888114f,  -0.02798376941698385f,  -0.6308807679295904f,
    0.7148465705525415f,   -0.23037781330885523f };

// Register-resident cascade (round-5 structure, best measured) minus the LDS
// transpose strips: each lane's conv outputs are already CONSECUTIVE in the
// output array, so direct per-lane float4/float2 nontemporal stores are fully
// coalesced (dense 1KB per wave-store) with zero LDS round-trip.
__global__ __launch_bounds__(NT, 8) void wavedec4_db4(const float* __restrict__ x,
                                                      float* __restrict__ out)
{
    __shared__ float hA[8 * HS];   // 16640 B : cA1 SoA, later cA3 [g&1][g>>1]
    __shared__ float hB[4 * HS];   //  8320 B : cA2 SoA [m*HS + t]
    const int t = threadIdx.x;
    const float* __restrict__ xr = x + blockIdx.x * (size_t)L0;
    float* __restrict__ outr = out + blockIdx.x * (size_t)ROW_OUT;

    // ---- load x window [16t-8, 16t+16) into registers, all loads up front ----
    float xw[24];
    if (t > 0) {
        const float4* p = (const float4*)(xr + 16 * t - 8);
        float4 v0 = p[0], v1 = p[1], v2 = p[2], v3 = p[3], v4 = p[4], v5 = p[5];
        xw[0] = v0.x;  xw[1] = v0.y;  xw[2] = v0.z;  xw[3] = v0.w;
        xw[4] = v1.x;  xw[5] = v1.y;  xw[6] = v1.z;  xw[7] = v1.w;
        xw[8] = v2.x;  xw[9] = v2.y;  xw[10] = v2.z; xw[11] = v2.w;
        xw[12] = v3.x; xw[13] = v3.y; xw[14] = v3.z; xw[15] = v3.w;
        xw[16] = v4.x; xw[17] = v4.y; xw[18] = v4.z; xw[19] = v4.w;
        xw[20] = v5.x; xw[21] = v5.y; xw[22] = v5.z; xw[23] = v5.w;
    } else {
        const float4* p = (const float4*)xr;
        float4 v0 = p[0], v1 = p[1], v2 = p[2], v3 = p[3];
        xw[8] = v0.x;  xw[9] = v0.y;  xw[10] = v0.z; xw[11] = v0.w;
        xw[12] = v1.x; xw[13] = v1.y; xw[14] = v1.z; xw[15] = v1.w;
        xw[16] = v2.x; xw[17] = v2.y; xw[18] = v2.z; xw[19] = v2.w;
        xw[20] = v3.x; xw[21] = v3.y; xw[22] = v3.z; xw[23] = v3.w;
#pragma unroll
        for (int k = 0; k < 8; ++k) xw[k] = xw[15 - k];   // xsym(k-8) = x[7-k]
    }

    // ---- L1: outputs i = 8t+m, taps xw[2m+2+j] ----
    float lo1[8], hi1[8];
#pragma unroll
    for (int m = 0; m < 8; ++m) {
        float l = 0.f, h = 0.f;
#pragma unroll
        for (int j = 0; j < 8; ++j) {
            float v = xw[2 * m + 2 + j];
            l = fmaf(GLO[j], v, l);
            h = fmaf(GHI[j], v, h);
        }
        lo1[m] = l;
        hi1[m] = h;
        hA[m * HS + t] = l;
    }
    {   // direct coalesced cD1 stores: lane holds cD1[8t..8t+7]
        f4u a = { hi1[0], hi1[1], hi1[2], hi1[3] };
        f4u b = { hi1[4], hi1[5], hi1[6], hi1[7] };
        __builtin_nontemporal_store(a, (f4u*)(outr + OFF_D1 + 8 * t));
        __builtin_nontemporal_store(b, (f4u*)(outr + OFF_D1 + 8 * t + 4));
    }
    if (t == NT - 1) {   // L1 tail i = 4096..4098, entirely from xw registers
#pragma unroll
        for (int e = 0; e < 3; ++e) {
            const int i = 4096 + e;
            float l = 0.f, h = 0.f;
#pragma unroll
            for (int j = 0; j < 8; ++j) {
                int q = 2 * i - 6 + j;                       // 8186..8202
                int idx = ((q <= 8191) ? q : (16383 - q)) - 8168;
                float v = xw[idx];
                l = fmaf(GLO[j], v, l);
                h = fmaf(GHI[j], v, h);
            }
            __builtin_nontemporal_store(h, outr + OFF_D1 + i);
            hA[(i & 7) * HS + (i >> 3)] = l;
        }
    }
    __syncthreads();

    // ---- L2: outputs j = 4t+m, taps w2[2m+j'] where w2[k] = cA1[8t-6+k] ----
    float w2[14];
#pragma unroll
    for (int k = 0; k < 6; ++k) {
        int g = 8 * t - 6 + k;
        if (g < 0) g = -1 - g;                 // front reflection (t=0 only)
        w2[k] = hA[(g & 7) * HS + (g >> 3)];
    }
#pragma unroll
    for (int m = 0; m < 8; ++m) w2[6 + m] = lo1[m];
    float lo2[4], hi2[4];
#pragma unroll
    for (int m = 0; m < 4; ++m) {
        float l = 0.f, h = 0.f;
#pragma unroll
        for (int j = 0; j < 8; ++j) {
            float v = w2[2 * m + j];
            l = fmaf(GLO[j], v, l);
            h = fmaf(GHI[j], v, h);
        }
        lo2[m] = l;
        hi2[m] = h;
        hB[m * HS + t] = l;
    }
    {   // direct coalesced cD2 store: lane holds cD2[4t..4t+3]
        f4u a = { hi2[0], hi2[1], hi2[2], hi2[3] };
        __builtin_nontemporal_store(a, (f4u*)(outr + OFF_D2 + 4 * t));
    }
    if (t < 5) {    // L2 tail: j = 2048..2052 from published cA1 (+tail reflection)
        const int jj = 2048 + t;
        float l = 0.f, h = 0.f;
#pragma unroll
        for (int j = 0; j < 8; ++j) {
            int g = 2 * jj - 6 + j;
            if (g > 4098) g = 8197 - g;        // reflect at N1
            float v = hA[(g & 7) * HS + (g >> 3)];
            l = fmaf(GLO[j], v, l);
            h = fmaf(GHI[j], v, h);
        }
        __builtin_nontemporal_store(h, outr + OFF_D2 + jj);
        hB[(jj & 3) * HS + (jj >> 2)] = l;
    }
    __syncthreads();

    // ---- L3: outputs j = 2t+m, taps w3[2m+j'] where w3[k] = cA2[4t-6+k] ----
    float w3[10];
#pragma unroll
    for (int k = 0; k < 6; ++k) {
        int g = 4 * t - 6 + k;
        if (g < 0) g = -1 - g;
        w3[k] = hB[(g & 3) * HS + (g >> 2)];
    }
#pragma unroll
    for (int m = 0; m < 4; ++m) w3[6 + m] = lo2[m];
    float lo3[2], hi3[2];
#pragma unroll
    for (int m = 0; m < 2; ++m) {
        float l = 0.f, h = 0.f;
#pragma unroll
        for (int j = 0; j < 8; ++j) {
            float v = w3[2 * m + j];
            l = fmaf(GLO[j], v, l);
            h = fmaf(GHI[j], v, h);
        }
        lo3[m] = l;
        hi3[m] = h;
        hA[m * HS + t] = l;                    // cA3 pair view: (2t+m)&1=m, >>1=t
    }
    {   // direct coalesced cD3 store: lane holds cD3[2t..2t+1]
        f2u a = { hi3[0], hi3[1] };
        __builtin_nontemporal_store(a, (f2u*)(outr + OFF_D3 + 2 * t));
    }
    if (t < 6) {    // L3 tail: j = 1024..1029 from published cA2 (+reflection)
        const int jj = 1024 + t;
        float l = 0.f, h = 0.f;
#pragma unroll
        for (int j = 0; j < 8; ++j) {
            int g = 2 * jj - 6 + j;
            if (g > 2052) g = 4105 - g;        // reflect at N2
            float v = hB[(g & 3) * HS + (g >> 2)];
            l = fmaf(GLO[j], v, l);
            h = fmaf(GHI[j], v, h);
        }
        __builtin_nontemporal_store(h, outr + OFF_D3 + jj);
        hA[(jj & 1) * HS + (jj >> 1)] = l;
    }
    __syncthreads();

    // ---- L4: output j = t, taps w4[j'] where w4[k] = cA3[2t-6+k] ----
    float w4[8];
#pragma unroll
    for (int k = 0; k < 6; ++k) {
        int g = 2 * t - 6 + k;
        if (g < 0) g = -1 - g;
        w4[k] = hA[(g & 1) * HS + (g >> 1)];
    }
    w4[6] = lo3[0];
    w4[7] = lo3[1];
    {
        float l = 0.f, h = 0.f;
#pragma unroll
        for (int j = 0; j < 8; ++j) {
            float v = w4[j];
            l = fmaf(GLO[j], v, l);
            h = fmaf(GHI[j], v, h);
        }
        __builtin_nontemporal_store(l, outr + OFF_A4 + t);   // lane-consecutive
        __builtin_nontemporal_store(h, outr + OFF_D4 + t);
    }
    if (t < 6) {    // L4 tail: j = 512..517 from published cA3 (+reflection)
        const int jj = 512 + t;
        float l = 0.f, h = 0.f;
#pragma unroll
        for (int j = 0; j < 8; ++j) {
            int g = 2 * jj - 6 + j;
            if (g > 1029) g = 2059 - g;        // reflect at N3
            float v = hA[(g & 1) * HS + (g >> 1)];
            l = fmaf(GLO[j], v, l);
            h = fmaf(GHI[j], v, h);
        }
        __builtin_nontemporal_store(l, outr + OFF_A4 + jj);
        __builtin_nontemporal_store(h, outr + OFF_D4 + jj);
    }
}

extern "C" void kernel_launch(void* const* d_in, const int* in_sizes, int n_in,
                              void* d_out, int out_size, void* d_ws, size_t ws_size,
                              hipStream_t stream) {
    const float* x = (const float*)d_in[0];
    float* out = (float*)d_out;
    const int rows = in_sizes[0] / L0;  // 64*32 = 2048
    wavedec4_db4<<<dim3(rows), dim3(NT), 0, stream>>>(x, out);
}